// Round 9
// baseline (134.563 us; speedup 1.0000x reference)
//
#include <hip/hip_runtime.h>
#include <stdint.h>

#define B_ 32
#define S_ 32
#define P_ 2048
#define J_ 32
#define I_ 16

// U layout: [b][s][p][jpair] dwords; one row = 16 dwords (32 fp16 j's)
#define UROW 16
#define UBSTRIDE ((size_t)S_ * P_ * UROW)   // per-b plane = 4 MiB

typedef _Float16 half8_t __attribute__((ext_vector_type(8)));
typedef float f32x16 __attribute__((ext_vector_type(16)));
typedef uint32_t u32x4 __attribute__((ext_vector_type(4)));

// fp16 unpack helpers (dword = {lo: j=2k, hi: j=2k+1} of one b-row)
__device__ inline float f16lo(uint32_t d) {
    return (float)__builtin_bit_cast(_Float16, (unsigned short)(d & 0xffffu));
}
__device__ inline float f16hi(uint32_t d) {
    return (float)__builtin_bit_cast(_Float16, (unsigned short)(d >> 16));
}

// =====================================================================
// Kernel 1 (MFMA): per (s,p), C[b=32,j=32] = X[b,:].W[j,:]^T via one
// v_mfma_f32_32x32x16_f16.
// R8 post-mortem: uhat pinned at ~80us (2.5 TB/s) across 3 different
// instruction mixes -> memory-mix bound: U's 128MB write thrashes L3
// against W. Fixes here:
//  (a) NT stores: U streams to HBM, L3 keeps W+X only.
//  (b) in-wave row-pair packing (1 shfl_xor + ~4 VALU per pair) to
//      SINGLE-b layout U[b][s][p][jpair] so routing loads each dword
//      exactly once (R8's interleaved format forced 2x load volume).
// Packing: rows r(even),r+1 differ only by b+1. hp={h[r],h[r+1]};
// exchange with lane^1; even lane emits row r dword {j,j+1}, odd lane
// row r+1. Store: 4x 64B dense segments per instruction.
// =====================================================================
__global__ __launch_bounds__(256) void uhat_kernel(
        const float* __restrict__ W, const float* __restrict__ X,
        uint32_t* __restrict__ U) {
    const int tid  = threadIdx.x;
    const int lane = tid & 63;
    const int wave = tid >> 6;
    const int l31  = lane & 31;
    const int lhi  = lane >> 5;       // 0/1
    const int lpar = lane & 1;        // row-parity this lane emits
    const int s    = blockIdx.y;
    const int p0   = blockIdx.x * 16 + wave * 4;

    float4 wv[4][2], xv[4][2];
    #pragma unroll
    for (int t = 0; t < 4; ++t) {
        const int p = p0 + t;
        const float* wr = W + (((size_t)s * P_ + p) * J_ + l31) * I_ + lhi * 8;
        wv[t][0] = *reinterpret_cast<const float4*>(wr);
        wv[t][1] = *reinterpret_cast<const float4*>(wr + 4);
        const float* xr = X + ((size_t)l31 * P_ + p) * I_ + lhi * 8;
        xv[t][0] = *reinterpret_cast<const float4*>(xr);
        xv[t][1] = *reinterpret_cast<const float4*>(xr + 4);
    }

    #pragma unroll
    for (int t = 0; t < 4; ++t) {
        const int p = p0 + t;
        half8_t A, Bf;
        A[0] = (_Float16)xv[t][0].x; A[1] = (_Float16)xv[t][0].y;
        A[2] = (_Float16)xv[t][0].z; A[3] = (_Float16)xv[t][0].w;
        A[4] = (_Float16)xv[t][1].x; A[5] = (_Float16)xv[t][1].y;
        A[6] = (_Float16)xv[t][1].z; A[7] = (_Float16)xv[t][1].w;
        Bf[0] = (_Float16)wv[t][0].x; Bf[1] = (_Float16)wv[t][0].y;
        Bf[2] = (_Float16)wv[t][0].z; Bf[3] = (_Float16)wv[t][0].w;
        Bf[4] = (_Float16)wv[t][1].x; Bf[5] = (_Float16)wv[t][1].y;
        Bf[6] = (_Float16)wv[t][1].z; Bf[7] = (_Float16)wv[t][1].w;

        f32x16 acc = {};
        acc = __builtin_amdgcn_mfma_f32_32x32x16_f16(A, Bf, acc, 0, 0, 0);

        // acc[r]: j = l31, b = (r&3)+8*(r>>2)+4*lhi (HW-verified m74/m101)
        const size_t rowbase = ((size_t)s * P_ + p) * UROW + (l31 >> 1);
        #pragma unroll
        for (int rp = 0; rp < 8; ++rp) {
            const int r = 2 * rp;
            uint32_t lo16 = (uint32_t)__builtin_bit_cast(
                unsigned short, (_Float16)acc[r]);       // row r   (RNE)
            uint32_t hi16 = (uint32_t)__builtin_bit_cast(
                unsigned short, (_Float16)acc[r + 1]);   // row r+1 (RNE)
            uint32_t hp = lo16 | (hi16 << 16);
            uint32_t tp = (uint32_t)__shfl_xor((int)hp, 1, 64);
            // even lane: row r  dword {my j, partner j+1}
            // odd  lane: row r+1 dword {partner j-1, my j}
            uint32_t d = lpar ? ((tp >> 16) | (hp & 0xffff0000u))
                              : ((hp & 0xffffu) | (tp << 16));
            const int b = (r & 3) + lpar + 8 * (r >> 2) + 4 * lhi;
            __builtin_nontemporal_store(d, &U[(size_t)b * UBSTRIDE + rowbase]);
        }
    }
}

// ---------- split-butterfly wave reduction of a 32-vector ----------
template <int MASK, int HALF>
__device__ inline void red_level(float* red, int lane) {
    const bool hi = (lane & MASK) != 0;
    #pragma unroll
    for (int k = 0; k < HALF; ++k) {
        float send = hi ? red[k] : red[k + HALF];
        float recv = __shfl_xor(send, MASK, 64);
        red[k] = (hi ? red[k + HALF] : red[k]) + recv;
    }
}

// =====================================================================
// Kernel 2: dynamic routing. One 1024-thread block per (b,s) — R5's
// proven 22us structure. Thread owns p-rows 2*tid, 2*tid+1: 32 dwords
// = 128B contiguous, loaded ONCE (NT: don't evict W from L3).
// =====================================================================
__global__ __launch_bounds__(1024) void routing_kernel(
        const uint32_t* __restrict__ U, float* __restrict__ out) {
    const int tid  = threadIdx.x;
    const int lane = tid & 63;
    const int wid  = tid >> 6;            // 0..15
    const int bs   = blockIdx.x;          // b*S_ + s

    __shared__ float sred[16 * 32];       // per-wave 32-vector partials
    __shared__ float vlds[32];
    __shared__ float scal[32];            // [0..15] max, [16..31] sum

    // load my 2 rows: 32 dwords = 128B contiguous
    const u32x4* ub = reinterpret_cast<const u32x4*>(
        U + (size_t)bs * ((size_t)P_ * UROW) + (size_t)tid * 32);
    uint32_t a[32];
    #pragma unroll
    for (int k = 0; k < 8; ++k) {
        u32x4 t = __builtin_nontemporal_load(&ub[k]);
        a[k * 4 + 0] = t[0]; a[k * 4 + 1] = t[1];
        a[k * 4 + 2] = t[2]; a[k * 4 + 3] = t[3];
    }
    // a[0..15] = row p0 (j-pair dwords), a[16..31] = row p1

    float bp0 = 0.0f, bp1 = 0.0f;         // routing logits for my two p's

    for (int it = 0; it < 3; ++it) {
        // ---- c = softmax(b) over p ----
        float c0, c1;
        if (it == 0) {
            c0 = c1 = 1.0f / 2048.0f;     // softmax of zeros, exact
        } else {
            float mx = fmaxf(bp0, bp1);
            #pragma unroll
            for (int msk = 32; msk >= 1; msk >>= 1)
                mx = fmaxf(mx, __shfl_xor(mx, msk, 64));
            if (lane == 0) scal[wid] = mx;
            __syncthreads();
            mx = scal[0];
            #pragma unroll
            for (int w2 = 1; w2 < 16; ++w2) mx = fmaxf(mx, scal[w2]);
            float e0 = __expf(bp0 - mx);
            float e1 = __expf(bp1 - mx);
            float zs = e0 + e1;
            #pragma unroll
            for (int msk = 32; msk >= 1; msk >>= 1)
                zs += __shfl_xor(zs, msk, 64);
            if (lane == 0) scal[16 + wid] = zs;
            __syncthreads();
            float Z = 0.0f;
            #pragma unroll
            for (int w2 = 0; w2 < 16; ++w2) Z += scal[16 + w2];
            float invZ = 1.0f / Z;
            c0 = e0 * invZ;
            c1 = e1 * invZ;
        }

        // ---- per-thread partial s_j = c0*u[p0][j] + c1*u[p1][j] ----
        float red[32];
        #pragma unroll
        for (int k = 0; k < 16; ++k) {
            uint32_t d0 = a[k], d1 = a[16 + k];
            red[2 * k]     = fmaf(c0, f16lo(d0), c1 * f16lo(d1));
            red[2 * k + 1] = fmaf(c0, f16hi(d0), c1 * f16hi(d1));
        }
        // ---- wave reduce-scatter (31 shfl total) ----
        red_level<32, 16>(red, lane);
        red_level<16, 8>(red, lane);
        red_level<8, 4>(red, lane);
        red_level<4, 2>(red, lane);
        red_level<2, 1>(red, lane);
        red[0] += __shfl_xor(red[0], 1, 64);   // lane holds s_{lane>>1} wave-sum
        if ((lane & 1) == 0) sred[wid * 32 + (lane >> 1)] = red[0];
        __syncthreads();

        // ---- cross-wave finalize + squash (first 32 threads) ----
        if (tid < 32) {
            float sv = 0.0f;
            #pragma unroll
            for (int w2 = 0; w2 < 16; ++w2) sv += sred[w2 * 32 + tid];
            float sq = sv * sv;
            #pragma unroll
            for (int msk = 16; msk >= 1; msk >>= 1)
                sq += __shfl_xor(sq, msk, 64);
            float n = sqrtf(sq);
            float scale = sq / ((1.0f + sq) * (n + 1e-7f));
            float v = sv * scale;
            vlds[tid] = v;
            if (it == 2) out[(size_t)bs * J_ + tid] = v;
        }
        __syncthreads();

        // ---- agreement + logit update (not needed after last iter) ----
        if (it < 2) {
            const float2* vl2 = reinterpret_cast<const float2*>(vlds);
            float ag0 = 0.0f, ag1 = 0.0f;
            #pragma unroll
            for (int k = 0; k < 16; ++k) {
                float2 vk = vl2[k];               // v[2k], v[2k+1] (LDS broadcast)
                uint32_t d0 = a[k], d1 = a[16 + k];
                ag0 = fmaf(vk.x, f16lo(d0), ag0);
                ag0 = fmaf(vk.y, f16hi(d0), ag0);
                ag1 = fmaf(vk.x, f16lo(d1), ag1);
                ag1 = fmaf(vk.y, f16hi(d1), ag1);
            }
            bp0 += ag0;
            bp1 += ag1;
        }
    }
}

extern "C" void kernel_launch(void* const* d_in, const int* in_sizes, int n_in,
                              void* d_out, int out_size, void* d_ws, size_t ws_size,
                              hipStream_t stream) {
    (void)in_sizes; (void)n_in; (void)out_size;
    const float* X = (const float*)d_in[0];        // [B,P,I] fp32
    const float* W = (const float*)d_in[1];        // [S,P,J,I] fp32
    float* out     = (float*)d_out;                // [B,S,J] fp32
    uint32_t* U    = (uint32_t*)d_ws;              // fp16 u_hat [b][s][p][jpair]

    const size_t need = (size_t)B_ * S_ * P_ * J_ * 2;  // 128 MiB
    if (ws_size < need) return;  // cannot run without scratch

    dim3 g1(P_ / 16, S_);
    uhat_kernel<<<g1, 256, 0, stream>>>(W, X, U);
    routing_kernel<<<B_ * S_, 1024, 0, stream>>>(U, out);
}

// Round 10
// 104.766 us; speedup vs baseline: 1.2844x; 1.2844x over previous
//
#include <hip/hip_runtime.h>
#include <stdint.h>

#define B_ 32
#define S_ 32
#define P_ 2048
#define J_ 32
#define I_ 16

// U layout: single-b rows. U[b][s][p][jp] dwords, jp = j-pair (16/row).
#define UROW 16
#define UBSTRIDE ((size_t)S_ * P_ * UROW)   // per-b plane = 4 MiB

typedef _Float16 half8_t __attribute__((ext_vector_type(8)));
typedef float f32x16 __attribute__((ext_vector_type(16)));

// fp16 unpack helpers (dword = {lo: j=2k, hi: j=2k+1} of one b-row)
__device__ inline float f16lo(uint32_t d) {
    return (float)__builtin_bit_cast(_Float16, (unsigned short)(d & 0xffffu));
}
__device__ inline float f16hi(uint32_t d) {
    return (float)__builtin_bit_cast(_Float16, (unsigned short)(d >> 16));
}

// =====================================================================
// Kernel 1 (MFMA): per (s,p), C[b=32,j=32] = X[b,:].W[j,:]^T via one
// v_mfma_f32_32x32x16_f16.
// R9 post-mortem: R3==R5==R8==~80us across instruction mixes; R9's
// 64B-segment stores regressed (+18us). This round: single-b layout
// (routing reads 1x = 22us, R5-proven) with a WAVE-PRIVATE LDS dword
// transpose (no barrier):
//   pack: acc pairs -> single-b dword via 1 shfl (R9-proven correct)
//   LDS write: [t][b][g] + XOR swizzle (2-way, free)
//   LDS read:  8x ds_read_b128 per lane (data-bound)
//   store: 8x dwordx4/lane; per instr 4 b-planes x 256B DENSE segments
// =====================================================================
__global__ __launch_bounds__(256) void uhat_kernel(
        const float* __restrict__ W, const float* __restrict__ X,
        uint32_t* __restrict__ U) {
    const int tid  = threadIdx.x;
    const int lane = tid & 63;
    const int wave = tid >> 6;
    const int l31  = lane & 31;
    const int lhi  = lane >> 5;       // 0/1
    const int lpar = lane & 1;        // row-parity this lane emits
    const int s    = blockIdx.y;
    const int p0   = blockIdx.x * 16 + wave * 4;

    // wave-private transpose slab: [4 t][32 b][16 g] dwords = 8KB/wave
    __shared__ uint32_t xs[4][2048];

    float4 wv[4][2], xv[4][2];
    #pragma unroll
    for (int t = 0; t < 4; ++t) {
        const int p = p0 + t;
        const float* wr = W + (((size_t)s * P_ + p) * J_ + l31) * I_ + lhi * 8;
        wv[t][0] = *reinterpret_cast<const float4*>(wr);
        wv[t][1] = *reinterpret_cast<const float4*>(wr + 4);
        const float* xr = X + ((size_t)l31 * P_ + p) * I_ + lhi * 8;
        xv[t][0] = *reinterpret_cast<const float4*>(xr);
        xv[t][1] = *reinterpret_cast<const float4*>(xr + 4);
    }

    const int g  = l31 >> 1;          // jpair index 0..15
    const int gq = g >> 2, ge = g & 3;

    #pragma unroll
    for (int t = 0; t < 4; ++t) {
        half8_t A, Bf;
        A[0] = (_Float16)xv[t][0].x; A[1] = (_Float16)xv[t][0].y;
        A[2] = (_Float16)xv[t][0].z; A[3] = (_Float16)xv[t][0].w;
        A[4] = (_Float16)xv[t][1].x; A[5] = (_Float16)xv[t][1].y;
        A[6] = (_Float16)xv[t][1].z; A[7] = (_Float16)xv[t][1].w;
        Bf[0] = (_Float16)wv[t][0].x; Bf[1] = (_Float16)wv[t][0].y;
        Bf[2] = (_Float16)wv[t][0].z; Bf[3] = (_Float16)wv[t][0].w;
        Bf[4] = (_Float16)wv[t][1].x; Bf[5] = (_Float16)wv[t][1].y;
        Bf[6] = (_Float16)wv[t][1].z; Bf[7] = (_Float16)wv[t][1].w;

        f32x16 acc = {};
        acc = __builtin_amdgcn_mfma_f32_32x32x16_f16(A, Bf, acc, 0, 0, 0);

        // pack rows (r, r+1) = (b0, b0+1) at col j=l31 into single-b
        // dwords (R9-proven), write to swizzled LDS slab
        #pragma unroll
        for (int m = 0; m < 8; ++m) {
            const int r = 2 * m;
            uint32_t lo16 = (uint32_t)__builtin_bit_cast(
                unsigned short, (_Float16)acc[r]);       // b0   (RNE)
            uint32_t hi16 = (uint32_t)__builtin_bit_cast(
                unsigned short, (_Float16)acc[r + 1]);   // b0+1 (RNE)
            uint32_t hp = lo16 | (hi16 << 16);
            uint32_t tp = (uint32_t)__shfl_xor((int)hp, 1, 64);
            uint32_t d = lpar ? ((tp >> 16) | (hp & 0xffff0000u))
                              : ((hp & 0xffffu) | (tp << 16));
            const int b = (r & 3) + lpar + 8 * (r >> 2) + 4 * lhi;
            const int k = (b >> 1) & 3;
            xs[wave][t * 512 + b * 16 + (((gq ^ k ^ t) & 3) << 2) + ge] = d;
        }
    }

    // wave-local read-back (no __syncthreads: slab is wave-private;
    // compiler inserts lgkmcnt waits) + dense dwordx4 stores.
    const int Lh  = lane >> 4;        // 0..3
    const int tr  = (lane >> 2) & 3;  // p-offset within wave
    const int gqr = lane & 3;         // jp-group
    const int p   = p0 + tr;
    #pragma unroll
    for (int i = 0; i < 8; ++i) {
        const int b = 4 * i + Lh;
        const int k = (b >> 1) & 3;
        const int addr = tr * 512 + b * 16 + (((gqr ^ k ^ tr) & 3) << 2);
        uint4 vv = *reinterpret_cast<const uint4*>(&xs[wave][addr]);
        *reinterpret_cast<uint4*>(
            U + (size_t)b * UBSTRIDE + ((size_t)s * P_ + p) * UROW + 4 * gqr) = vv;
    }
}

// ---------- split-butterfly wave reduction of a 32-vector ----------
template <int MASK, int HALF>
__device__ inline void red_level(float* red, int lane) {
    const bool hi = (lane & MASK) != 0;
    #pragma unroll
    for (int k = 0; k < HALF; ++k) {
        float send = hi ? red[k] : red[k + HALF];
        float recv = __shfl_xor(send, MASK, 64);
        red[k] = (hi ? red[k + HALF] : red[k]) + recv;
    }
}

// =====================================================================
// Kernel 2: dynamic routing. One 1024-thread block per (b,s) — R5's
// proven 22us structure, verbatim. Thread owns p-rows 2*tid, 2*tid+1:
// 32 dwords = 128B contiguous, loaded ONCE. Plain loads (no NT).
// =====================================================================
__global__ __launch_bounds__(1024) void routing_kernel(
        const uint32_t* __restrict__ U, float* __restrict__ out) {
    const int tid  = threadIdx.x;
    const int lane = tid & 63;
    const int wid  = tid >> 6;            // 0..15
    const int bs   = blockIdx.x;          // b*S_ + s

    __shared__ float sred[16 * 32];       // per-wave 32-vector partials
    __shared__ float vlds[32];
    __shared__ float scal[32];            // [0..15] max, [16..31] sum

    // load my 2 rows: 32 dwords = 128B contiguous
    const uint32_t* ub = U + (size_t)bs * ((size_t)P_ * UROW) + (size_t)tid * 32;
    uint32_t a[32];
    #pragma unroll
    for (int k = 0; k < 8; ++k) {
        uint4 t = reinterpret_cast<const uint4*>(ub)[k];
        a[k * 4 + 0] = t.x; a[k * 4 + 1] = t.y;
        a[k * 4 + 2] = t.z; a[k * 4 + 3] = t.w;
    }
    // a[0..15] = row p0 (j-pair dwords), a[16..31] = row p1

    float bp0 = 0.0f, bp1 = 0.0f;         // routing logits for my two p's

    for (int it = 0; it < 3; ++it) {
        // ---- c = softmax(b) over p ----
        float c0, c1;
        if (it == 0) {
            c0 = c1 = 1.0f / 2048.0f;     // softmax of zeros, exact
        } else {
            float mx = fmaxf(bp0, bp1);
            #pragma unroll
            for (int msk = 32; msk >= 1; msk >>= 1)
                mx = fmaxf(mx, __shfl_xor(mx, msk, 64));
            if (lane == 0) scal[wid] = mx;
            __syncthreads();
            mx = scal[0];
            #pragma unroll
            for (int w2 = 1; w2 < 16; ++w2) mx = fmaxf(mx, scal[w2]);
            float e0 = __expf(bp0 - mx);
            float e1 = __expf(bp1 - mx);
            float zs = e0 + e1;
            #pragma unroll
            for (int msk = 32; msk >= 1; msk >>= 1)
                zs += __shfl_xor(zs, msk, 64);
            if (lane == 0) scal[16 + wid] = zs;
            __syncthreads();
            float Z = 0.0f;
            #pragma unroll
            for (int w2 = 0; w2 < 16; ++w2) Z += scal[16 + w2];
            float invZ = 1.0f / Z;
            c0 = e0 * invZ;
            c1 = e1 * invZ;
        }

        // ---- per-thread partial s_j = c0*u[p0][j] + c1*u[p1][j] ----
        float red[32];
        #pragma unroll
        for (int k = 0; k < 16; ++k) {
            uint32_t d0 = a[k], d1 = a[16 + k];
            red[2 * k]     = fmaf(c0, f16lo(d0), c1 * f16lo(d1));
            red[2 * k + 1] = fmaf(c0, f16hi(d0), c1 * f16hi(d1));
        }
        // ---- wave reduce-scatter (31 shfl total) ----
        red_level<32, 16>(red, lane);
        red_level<16, 8>(red, lane);
        red_level<8, 4>(red, lane);
        red_level<4, 2>(red, lane);
        red_level<2, 1>(red, lane);
        red[0] += __shfl_xor(red[0], 1, 64);   // lane holds s_{lane>>1} wave-sum
        if ((lane & 1) == 0) sred[wid * 32 + (lane >> 1)] = red[0];
        __syncthreads();

        // ---- cross-wave finalize + squash (first 32 threads) ----
        if (tid < 32) {
            float sv = 0.0f;
            #pragma unroll
            for (int w2 = 0; w2 < 16; ++w2) sv += sred[w2 * 32 + tid];
            float sq = sv * sv;
            #pragma unroll
            for (int msk = 16; msk >= 1; msk >>= 1)
                sq += __shfl_xor(sq, msk, 64);
            float n = sqrtf(sq);
            float scale = sq / ((1.0f + sq) * (n + 1e-7f));
            float v = sv * scale;
            vlds[tid] = v;
            if (it == 2) out[(size_t)bs * J_ + tid] = v;
        }
        __syncthreads();

        // ---- agreement + logit update (not needed after last iter) ----
        if (it < 2) {
            const float2* vl2 = reinterpret_cast<const float2*>(vlds);
            float ag0 = 0.0f, ag1 = 0.0f;
            #pragma unroll
            for (int k = 0; k < 16; ++k) {
                float2 vk = vl2[k];               // v[2k], v[2k+1] (LDS broadcast)
                uint32_t d0 = a[k], d1 = a[16 + k];
                ag0 = fmaf(vk.x, f16lo(d0), ag0);
                ag0 = fmaf(vk.y, f16hi(d0), ag0);
                ag1 = fmaf(vk.x, f16lo(d1), ag1);
                ag1 = fmaf(vk.y, f16hi(d1), ag1);
            }
            bp0 += ag0;
            bp1 += ag1;
        }
    }
}

extern "C" void kernel_launch(void* const* d_in, const int* in_sizes, int n_in,
                              void* d_out, int out_size, void* d_ws, size_t ws_size,
                              hipStream_t stream) {
    (void)in_sizes; (void)n_in; (void)out_size;
    const float* X = (const float*)d_in[0];        // [B,P,I] fp32
    const float* W = (const float*)d_in[1];        // [S,P,J,I] fp32
    float* out     = (float*)d_out;                // [B,S,J] fp32
    uint32_t* U    = (uint32_t*)d_ws;              // fp16 u_hat [b][s][p][jp]

    const size_t need = (size_t)B_ * S_ * P_ * J_ * 2;  // 128 MiB
    if (ws_size < need) return;  // cannot run without scratch

    dim3 g1(P_ / 16, S_);
    uhat_kernel<<<g1, 256, 0, stream>>>(W, X, U);
    routing_kernel<<<B_ * S_, 1024, 0, stream>>>(U, out);
}

// Round 11
// 99.586 us; speedup vs baseline: 1.3512x; 1.0520x over previous
//
#include <hip/hip_runtime.h>
#include <stdint.h>

#define B_ 32
#define S_ 32
#define P_ 2048
#define J_ 32
#define I_ 16
#define STILE 8

// U layout: single-b rows. U[b][s][p][jp] dwords, jp = j-pair (16/row).
#define UROW 16
#define UBSTRIDE ((size_t)S_ * P_ * UROW)   // per-b plane = 4 MiB

typedef _Float16 half8_t __attribute__((ext_vector_type(8)));
typedef float f32x16 __attribute__((ext_vector_type(16)));

// fp16 unpack helpers (dword = {lo: j=2k, hi: j=2k+1} of one b-row)
__device__ inline float f16lo(uint32_t d) {
    return (float)__builtin_bit_cast(_Float16, (unsigned short)(d & 0xffffu));
}
__device__ inline float f16hi(uint32_t d) {
    return (float)__builtin_bit_cast(_Float16, (unsigned short)(d >> 16));
}

// =====================================================================
// Kernel 1 (MFMA, s-tiled): per (s,p), C[b=32,j=32] = X[b,:].W[j,:]^T.
// R10 post-mortem: 4 different uhat structures all ~80us. Invariant =
// traffic: W 128 + U 128 + X re-reads 128MB (4096 blocks x 32KB, no
// cross-s dedup) = 384MB @ 4.8 TB/s. THIS ROUND: the A-frag (X) is
// s-INDEPENDENT -> tile 8 s per block, X-frags in registers ONCE
// (X traffic 128->16MB). W double-buffered in regs (prefetch s+1).
// Pack + wave-private LDS transpose + 256B-segment stores: R10 verbatim.
// =====================================================================
__global__ __launch_bounds__(256) void uhat_kernel(
        const float* __restrict__ W, const float* __restrict__ X,
        uint32_t* __restrict__ U) {
    const int tid  = threadIdx.x;
    const int lane = tid & 63;
    const int wave = tid >> 6;
    const int l31  = lane & 31;
    const int lhi  = lane >> 5;       // 0/1
    const int lpar = lane & 1;        // row-parity this lane emits
    const int sb   = blockIdx.y * STILE;
    const int p0   = blockIdx.x * 16 + wave * 4;

    // wave-private transpose slab: [4 t][32 b][16 g] dwords = 8KB/wave
    __shared__ uint32_t xs[4][2048];

    // ---- X fragments: s-independent. Load + cvt ONCE. ----
    half8_t xh[4];
    #pragma unroll
    for (int t = 0; t < 4; ++t) {
        const float* xr = X + ((size_t)l31 * P_ + (p0 + t)) * I_ + lhi * 8;
        float4 x0 = *reinterpret_cast<const float4*>(xr);
        float4 x1 = *reinterpret_cast<const float4*>(xr + 4);
        xh[t][0] = (_Float16)x0.x; xh[t][1] = (_Float16)x0.y;
        xh[t][2] = (_Float16)x0.z; xh[t][3] = (_Float16)x0.w;
        xh[t][4] = (_Float16)x1.x; xh[t][5] = (_Float16)x1.y;
        xh[t][6] = (_Float16)x1.z; xh[t][7] = (_Float16)x1.w;
    }

    const int g   = l31 >> 1;         // jpair index 0..15
    const int gq  = g >> 2, ge = g & 3;
    const int Lh  = lane >> 4;        // store-phase: b sub-index
    const int tr  = (lane >> 2) & 3;  // store-phase: p-offset in wave
    const int gqr = lane & 3;         // store-phase: jp-group

    // ---- W double buffer (registers) ----
    float4 wv[2][4][2];
    #pragma unroll
    for (int t = 0; t < 4; ++t) {
        const float* wr = W + (((size_t)sb * P_ + (p0 + t)) * J_ + l31) * I_ + lhi * 8;
        wv[0][t][0] = *reinterpret_cast<const float4*>(wr);
        wv[0][t][1] = *reinterpret_cast<const float4*>(wr + 4);
    }

    #pragma unroll
    for (int ss = 0; ss < STILE; ++ss) {
        const int cur = ss & 1, nxt = cur ^ 1;
        if (ss + 1 < STILE) {         // prefetch W for s+1
            #pragma unroll
            for (int t = 0; t < 4; ++t) {
                const float* wr = W + (((size_t)(sb + ss + 1) * P_ + (p0 + t)) * J_
                                        + l31) * I_ + lhi * 8;
                wv[nxt][t][0] = *reinterpret_cast<const float4*>(wr);
                wv[nxt][t][1] = *reinterpret_cast<const float4*>(wr + 4);
            }
        }
        const int s = sb + ss;

        #pragma unroll
        for (int t = 0; t < 4; ++t) {
            half8_t Bf;
            Bf[0] = (_Float16)wv[cur][t][0].x; Bf[1] = (_Float16)wv[cur][t][0].y;
            Bf[2] = (_Float16)wv[cur][t][0].z; Bf[3] = (_Float16)wv[cur][t][0].w;
            Bf[4] = (_Float16)wv[cur][t][1].x; Bf[5] = (_Float16)wv[cur][t][1].y;
            Bf[6] = (_Float16)wv[cur][t][1].z; Bf[7] = (_Float16)wv[cur][t][1].w;

            f32x16 acc = {};
            acc = __builtin_amdgcn_mfma_f32_32x32x16_f16(xh[t], Bf, acc, 0, 0, 0);

            // pack rows (r,r+1)=(b0,b0+1) at col j=l31 into single-b dwords
            // (R9-proven) and write to swizzled wave-private LDS slab
            #pragma unroll
            for (int m = 0; m < 8; ++m) {
                const int r = 2 * m;
                uint32_t lo16 = (uint32_t)__builtin_bit_cast(
                    unsigned short, (_Float16)acc[r]);       // b0   (RNE)
                uint32_t hi16 = (uint32_t)__builtin_bit_cast(
                    unsigned short, (_Float16)acc[r + 1]);   // b0+1 (RNE)
                uint32_t hp = lo16 | (hi16 << 16);
                uint32_t tp = (uint32_t)__shfl_xor((int)hp, 1, 64);
                uint32_t d = lpar ? ((tp >> 16) | (hp & 0xffff0000u))
                                  : ((hp & 0xffffu) | (tp << 16));
                const int b = (r & 3) + lpar + 8 * (r >> 2) + 4 * lhi;
                const int k = (b >> 1) & 3;
                xs[wave][t * 512 + b * 16 + (((gq ^ k ^ t) & 3) << 2) + ge] = d;
            }
        }

        // wave-local read-back (no barrier: slab is wave-private; the
        // compiler inserts lgkmcnt waits) + dense dwordx4 stores:
        // per instr, 4 b-planes x 256B dense segments.
        #pragma unroll
        for (int i = 0; i < 8; ++i) {
            const int b = 4 * i + Lh;
            const int k = (b >> 1) & 3;
            const int addr = tr * 512 + b * 16 + (((gqr ^ k ^ tr) & 3) << 2);
            uint4 vv = *reinterpret_cast<const uint4*>(&xs[wave][addr]);
            *reinterpret_cast<uint4*>(
                U + (size_t)b * UBSTRIDE + ((size_t)s * P_ + (p0 + tr)) * UROW
                  + 4 * gqr) = vv;
        }
    }
}

// ---------- split-butterfly wave reduction of a 32-vector ----------
template <int MASK, int HALF>
__device__ inline void red_level(float* red, int lane) {
    const bool hi = (lane & MASK) != 0;
    #pragma unroll
    for (int k = 0; k < HALF; ++k) {
        float send = hi ? red[k] : red[k + HALF];
        float recv = __shfl_xor(send, MASK, 64);
        red[k] = (hi ? red[k + HALF] : red[k]) + recv;
    }
}

// =====================================================================
// Kernel 2: dynamic routing. One 1024-thread block per (b,s) — R5/R10
// proven ~22us structure, verbatim. Thread owns p-rows 2*tid, 2*tid+1:
// 32 dwords = 128B contiguous, loaded ONCE.
// =====================================================================
__global__ __launch_bounds__(1024) void routing_kernel(
        const uint32_t* __restrict__ U, float* __restrict__ out) {
    const int tid  = threadIdx.x;
    const int lane = tid & 63;
    const int wid  = tid >> 6;            // 0..15
    const int bs   = blockIdx.x;          // b*S_ + s

    __shared__ float sred[16 * 32];       // per-wave 32-vector partials
    __shared__ float vlds[32];
    __shared__ float scal[32];            // [0..15] max, [16..31] sum

    // load my 2 rows: 32 dwords = 128B contiguous
    const uint32_t* ub = U + (size_t)bs * ((size_t)P_ * UROW) + (size_t)tid * 32;
    uint32_t a[32];
    #pragma unroll
    for (int k = 0; k < 8; ++k) {
        uint4 t = reinterpret_cast<const uint4*>(ub)[k];
        a[k * 4 + 0] = t.x; a[k * 4 + 1] = t.y;
        a[k * 4 + 2] = t.z; a[k * 4 + 3] = t.w;
    }
    // a[0..15] = row p0 (j-pair dwords), a[16..31] = row p1

    float bp0 = 0.0f, bp1 = 0.0f;         // routing logits for my two p's

    for (int it = 0; it < 3; ++it) {
        // ---- c = softmax(b) over p ----
        float c0, c1;
        if (it == 0) {
            c0 = c1 = 1.0f / 2048.0f;     // softmax of zeros, exact
        } else {
            float mx = fmaxf(bp0, bp1);
            #pragma unroll
            for (int msk = 32; msk >= 1; msk >>= 1)
                mx = fmaxf(mx, __shfl_xor(mx, msk, 64));
            if (lane == 0) scal[wid] = mx;
            __syncthreads();
            mx = scal[0];
            #pragma unroll
            for (int w2 = 1; w2 < 16; ++w2) mx = fmaxf(mx, scal[w2]);
            float e0 = __expf(bp0 - mx);
            float e1 = __expf(bp1 - mx);
            float zs = e0 + e1;
            #pragma unroll
            for (int msk = 32; msk >= 1; msk >>= 1)
                zs += __shfl_xor(zs, msk, 64);
            if (lane == 0) scal[16 + wid] = zs;
            __syncthreads();
            float Z = 0.0f;
            #pragma unroll
            for (int w2 = 0; w2 < 16; ++w2) Z += scal[16 + w2];
            float invZ = 1.0f / Z;
            c0 = e0 * invZ;
            c1 = e1 * invZ;
        }

        // ---- per-thread partial s_j = c0*u[p0][j] + c1*u[p1][j] ----
        float red[32];
        #pragma unroll
        for (int k = 0; k < 16; ++k) {
            uint32_t d0 = a[k], d1 = a[16 + k];
            red[2 * k]     = fmaf(c0, f16lo(d0), c1 * f16lo(d1));
            red[2 * k + 1] = fmaf(c0, f16hi(d0), c1 * f16hi(d1));
        }
        // ---- wave reduce-scatter (31 shfl total) ----
        red_level<32, 16>(red, lane);
        red_level<16, 8>(red, lane);
        red_level<8, 4>(red, lane);
        red_level<4, 2>(red, lane);
        red_level<2, 1>(red, lane);
        red[0] += __shfl_xor(red[0], 1, 64);   // lane holds s_{lane>>1} wave-sum
        if ((lane & 1) == 0) sred[wid * 32 + (lane >> 1)] = red[0];
        __syncthreads();

        // ---- cross-wave finalize + squash (first 32 threads) ----
        if (tid < 32) {
            float sv = 0.0f;
            #pragma unroll
            for (int w2 = 0; w2 < 16; ++w2) sv += sred[w2 * 32 + tid];
            float sq = sv * sv;
            #pragma unroll
            for (int msk = 16; msk >= 1; msk >>= 1)
                sq += __shfl_xor(sq, msk, 64);
            float n = sqrtf(sq);
            float scale = sq / ((1.0f + sq) * (n + 1e-7f));
            float v = sv * scale;
            vlds[tid] = v;
            if (it == 2) out[(size_t)bs * J_ + tid] = v;
        }
        __syncthreads();

        // ---- agreement + logit update (not needed after last iter) ----
        if (it < 2) {
            const float2* vl2 = reinterpret_cast<const float2*>(vlds);
            float ag0 = 0.0f, ag1 = 0.0f;
            #pragma unroll
            for (int k = 0; k < 16; ++k) {
                float2 vk = vl2[k];               // v[2k], v[2k+1] (LDS broadcast)
                uint32_t d0 = a[k], d1 = a[16 + k];
                ag0 = fmaf(vk.x, f16lo(d0), ag0);
                ag0 = fmaf(vk.y, f16hi(d0), ag0);
                ag1 = fmaf(vk.x, f16lo(d1), ag1);
                ag1 = fmaf(vk.y, f16hi(d1), ag1);
            }
            bp0 += ag0;
            bp1 += ag1;
        }
    }
}

extern "C" void kernel_launch(void* const* d_in, const int* in_sizes, int n_in,
                              void* d_out, int out_size, void* d_ws, size_t ws_size,
                              hipStream_t stream) {
    (void)in_sizes; (void)n_in; (void)out_size;
    const float* X = (const float*)d_in[0];        // [B,P,I] fp32
    const float* W = (const float*)d_in[1];        // [S,P,J,I] fp32
    float* out     = (float*)d_out;                // [B,S,J] fp32
    uint32_t* U    = (uint32_t*)d_ws;              // fp16 u_hat [b][s][p][jp]

    const size_t need = (size_t)B_ * S_ * P_ * J_ * 2;  // 128 MiB
    if (ws_size < need) return;  // cannot run without scratch

    dim3 g1(P_ / 16, S_ / STILE);
    uhat_kernel<<<g1, 256, 0, stream>>>(W, X, U);
    routing_kernel<<<B_ * S_, 1024, 0, stream>>>(U, out);
}